// Round 3
// baseline (204.324 us; speedup 1.0000x reference)
//
#include <hip/hip_runtime.h>
#include <hip/hip_bf16.h>

// RGCN layer: out = relu(x @ W_self^T + b + agg/deg)
// Pipeline v13 (5 dispatches): v12 + rebuilt GEMM
//   1. prep: xb = bf16(x), Bt = bf16([W_rel; W_self^T]), zero bucket cursors
//   2. coarse: edges -> 782 buckets of 64 dst-nodes; 4B packed records
//   3. fine: one block per bucket; LDS hist/scan/scatter -> (dst,rel)-sorted + x8 pad
//   4. aggregate: one wave per node; 8-batched edge loop, flush-on-rel-change
//   5. gemm: 64x128 tile, BK=64, double-buffered global_load_lds prefetch
//      (counted overlap: stage t+1 -> compute t -> vmcnt(0) -> raw s_barrier),
//      XOR piece-swizzle (both sides) for conflict-free ds_read_b128

#define D 128
#define RNUM 8
#define KREL (RNUM * D)      // 1024 — also A's row pitch
#define KTOT (KREL + D)      // 1152
#define BLK_M 64
#define BK 64                // gemm K-step (elems)

#define BSHIFT 6             // 64 nodes per bucket
#define BRANGE 64
#define BCAP   2048          // slots per bucket region (avg fill ~1250)
#define NBKT_MAX 784
#define CSTRIDE 16           // bucket cursor padding (ints) to spread atomic lines

typedef short short8 __attribute__((ext_vector_type(8)));
typedef float float4v __attribute__((ext_vector_type(4)));
typedef float float2v __attribute__((ext_vector_type(2)));

// fp32 -> bf16 round-nearest-even (bit pattern)
static __device__ __forceinline__ unsigned int f2b(float f) {
    unsigned int u = __float_as_uint(f);
    return (u + 0x7fffu + ((u >> 16) & 1u)) >> 16;
}
static __device__ __forceinline__ float b2f_lo(unsigned int u) {
    return __uint_as_float(u << 16);
}
static __device__ __forceinline__ float b2f_hi(unsigned int u) {
    return __uint_as_float(u & 0xffff0000u);
}

static __device__ __forceinline__ void gl_lds16(const void* g, void* l) {
    __builtin_amdgcn_global_load_lds(
        (const __attribute__((address_space(1))) unsigned int*)g,
        (__attribute__((address_space(3))) unsigned int*)l, 16, 0, 0);
}

// ---------- prep (3 block ranges): xb | Bt | zero bucket cursors ----------
__global__ void prep_kernel(const float* __restrict__ x,
                            const float* __restrict__ W_rel,
                            const float* __restrict__ W_self,
                            unsigned short* __restrict__ xb,
                            unsigned short* __restrict__ Bt,
                            int* __restrict__ gcur,
                            int Nn, int xb_blocks, int bt_blocks, int gz) {
    if (blockIdx.x < (unsigned)xb_blocks) {
        int t = blockIdx.x * 256 + threadIdx.x;
        int n = t >> 5;              // 32 threads/row, 4 cols each
        int c = (t & 31) * 4;
        if (n >= Nn) return;
        float4 v = *(const float4*)(x + (size_t)n * D + c);
        unsigned int p0 = f2b(v.x) | (f2b(v.y) << 16);
        unsigned int p1 = f2b(v.z) | (f2b(v.w) << 16);
        *(uint2*)(xb + (size_t)n * D + c) = make_uint2(p0, p1);
    } else if (blockIdx.x < (unsigned)(xb_blocks + bt_blocks)) {
        int idx = (blockIdx.x - xb_blocks) * 256 + threadIdx.x;
        if (idx >= 128 * KTOT) return;
        int o = idx / KTOT;
        int k = idx - o * KTOT;
        float v = (k < KREL) ? W_rel[(size_t)k * D + o]   // [r][d][o] flat = k*128+o
                             : W_self[(size_t)o * D + (k - KREL)];
        Bt[idx] = (unsigned short)f2b(v);
    } else {
        int idx = (blockIdx.x - xb_blocks - bt_blocks) * 256 + threadIdx.x;
        if (idx < gz) gcur[idx] = 0;
    }
}

// ---------- coarse: edges -> buckets, block-aggregated reservation ----------
__global__ __launch_bounds__(256) void coarse_kernel(
        const int* __restrict__ ei, const int* __restrict__ et,
        int* __restrict__ gcur, int* __restrict__ data, int E, int nbkt) {
    __shared__ int cnt[NBKT_MAX];
    int t = threadIdx.x;
    for (int i = t; i < nbkt; i += 256) cnt[i] = 0;
    __syncthreads();

    int rec[8], rb[8], rk[8];
    int e0 = blockIdx.x * 2048;
#pragma unroll
    for (int j = 0; j < 8; ++j) {
        int e = e0 + j * 256 + t;
        bool ok = e < E;
        int s = ok ? ei[e] : 0;
        int d = ok ? ei[E + e] : 0;
        int r = ok ? et[e] : 0;
        int bkt = d >> BSHIFT;
        rec[j] = s | ((d & (BRANGE - 1)) << 16) | (r << 22);
        rb[j] = ok ? bkt : -1;
        rk[j] = ok ? atomicAdd(&cnt[bkt], 1) : 0;
    }
    __syncthreads();

    // reserve global space per nonempty bucket; store absolute write base in cnt[]
    for (int i = t; i < nbkt; i += 256) {
        int c = cnt[i];
        if (c) cnt[i] = i * BCAP + atomicAdd(&gcur[i * CSTRIDE], c);
    }
    __syncthreads();

#pragma unroll
    for (int j = 0; j < 8; ++j) {
        if (rb[j] >= 0) {
            int pos = cnt[rb[j]] + rk[j];
            if (pos < (rb[j] + 1) * BCAP)   // capacity guard (never hit on sane data)
                data[pos] = rec[j];
        }
    }
}

// ---------- fine: one block per bucket; LDS hist + scan + in-place scatter ----------
__global__ __launch_bounds__(256) void fine_kernel(
        int* __restrict__ data, const int* __restrict__ gcur,
        int* __restrict__ offsets, int* __restrict__ deg, int Nn) {
    __shared__ int recs[BCAP];            // 8 KB
    __shared__ int hist[BRANGE * RNUM];   // 2 KB: counts, then converted to cursors
    int b = blockIdx.x;
    int t = threadIdx.x;
    int gbase = b * BCAP;
    int cnt = gcur[b * CSTRIDE];
    if (cnt > BCAP) cnt = BCAP;

    for (int i = t; i < BRANGE * RNUM; i += 256) hist[i] = 0;
    __syncthreads();

    // stage records to LDS + per-(node,rel) histogram (LDS atomics)
    for (int i = t; i < cnt; i += 256) {
        int rec = data[gbase + i];
        recs[i] = rec;
        int n = (rec >> 16) & (BRANGE - 1);
        int r = (rec >> 22) & 7;
        atomicAdd(&hist[n * RNUM + r], 1);
    }
    __syncthreads();

    // first wave: per-node padded scan, emit offsets/deg, sentinels, rel cursors
    if (t < BRANGE) {
        int dsum = 0;
#pragma unroll
        for (int r = 0; r < RNUM; ++r) dsum += hist[t * RNUM + r];
        int pad = (dsum + 7) & ~7;
        int x = pad;                       // inclusive scan across 64 lanes
        for (int off = 1; off < 64; off <<= 1) {
            int y = __shfl_up(x, off);
            if (t >= off) x += y;
        }
        int nb = gbase + (x - pad);        // node base (exclusive prefix)
        int n0 = b * BRANGE + t;
        if (n0 < Nn) { offsets[n0] = nb; deg[n0] = dsum; }
        for (int i = dsum; i < pad; ++i)
            data[nb + i] = (int)0xF0000000u;   // sentinel: rel 15
        int q = nb;
#pragma unroll
        for (int r = 0; r < RNUM; ++r) { int c = hist[t * RNUM + r]; hist[t * RNUM + r] = q; q += c; }
    }
    __syncthreads();

    // scatter in place (reads are fully staged in LDS)
    for (int i = t; i < cnt; i += 256) {
        int rec = recs[i];
        int n = (rec >> 16) & (BRANGE - 1);
        int r = (rec >> 22) & 7;
        int pos = atomicAdd(&hist[n * RNUM + r], 1);
        data[pos] = (rec & 0xFFFF) | (r << 28);
    }
}

// ---------- aggregation: one wave per node, rel-sorted flat stream, flush-on-change ----------
__global__ __launch_bounds__(256) void aggregate_kernel(
        const unsigned short* __restrict__ xb,
        const int* __restrict__ offsets,      // node base, multiple of 8
        const int* __restrict__ deg,          // real in-degree
        const int* __restrict__ sorted,       // src | rel<<28, sentinel 0xF0000000 padded
        unsigned short* __restrict__ A,       // [Nn][KREL]
        int Nn) {
    int node = blockIdx.x * 4 + (threadIdx.x >> 6);
    if (node >= Nn) return;
    int lane = threadIdx.x & 63;
    int laneoff = lane * 2;   // bf16-element offset within row

    // wave-uniform SGPR bounds -> uniform loop -> scalar loads of sorted[]
    int b0 = __builtin_amdgcn_readfirstlane(offsets[node]);
    int dg = __builtin_amdgcn_readfirstlane(deg[node]);
    int b1 = b0 + ((dg + 7) & ~7);
    float inv = 1.0f / fmaxf((float)dg, 1.0f);

    unsigned short* arow = A + (size_t)node * KREL + laneoff;

    unsigned wmask = 0;       // which rel rows have been written
    int cur = 8;              // current slot; 8 = trash (sentinels / start)
    float2v racc = {0.0f, 0.0f};

    // b1-b0 is a multiple of 8 by construction: always full 8-wide batches
    for (int e = b0; e < b1; e += 8) {
        int pv[8];
#pragma unroll
        for (int j = 0; j < 8; ++j)
            pv[j] = __builtin_amdgcn_readfirstlane(sorted[e + j]);   // SGPR
        unsigned int u[8];
#pragma unroll
        for (int j = 0; j < 8; ++j)
            u[j] = *(const unsigned int*)(xb + (size_t)(pv[j] & 0x0FFFFFFF) * D + laneoff);
#pragma unroll
        for (int j = 0; j < 8; ++j) {
            int r = ((unsigned)pv[j]) >> 28;          // uniform
            int si = (r < 8) ? r : 8;                 // sentinel -> trash slot
            float2v f;
            f.x = b2f_lo(u[j]);
            f.y = b2f_hi(u[j]);
            if (si != cur) {                          // uniform branch, ~9 taken/node
                if (cur < 8) {
                    *(unsigned int*)(arow + cur * D) =
                        f2b(racc.x * inv) | (f2b(racc.y * inv) << 16);
                    wmask |= 1u << cur;
                }
                cur = si;
                racc = f;
            } else {
                racc += f;
            }
        }
    }
    if (cur < 8) {
        *(unsigned int*)(arow + cur * D) =
            f2b(racc.x * inv) | (f2b(racc.y * inv) << 16);
        wmask |= 1u << cur;
    }
    // zero-fill rows for relations with no edges
#pragma unroll
    for (int r = 0; r < 8; ++r)
        if (!(wmask & (1u << r)))
            *(unsigned int*)(arow + r * D) = 0u;
}

// ---------- GEMM: out[64 x 128 tile] = relu([A|xb] @ Bt^T + b) ----------
// BK=64, double-buffered global_load_lds prefetch, XOR piece-swizzle (both sides).
__global__ __launch_bounds__(256) void gemm_kernel(
        const unsigned short* __restrict__ A,    // [.][KREL]
        const unsigned short* __restrict__ xb,   // [.][D] — self K-columns
        const unsigned short* __restrict__ Bt,
        const float* __restrict__ bias,
        float* __restrict__ out,
        int Nn) {
    __shared__ unsigned short As[2][BLK_M * BK];   // 2 x 8 KB
    __shared__ unsigned short Bs[2][128 * BK];     // 2 x 16 KB

    const int tid  = threadIdx.x;
    const int lane = tid & 63;
    const int w    = tid >> 6;
    const int wm   = w & 1;        // 2 m-slots of 32 rows
    const int wn   = w >> 1;       // 2 n-slots of 64 cols
    const int l16  = lane & 15;
    const int q    = lane >> 4;    // 0..3: 16B piece within K=32 fragment
    const int row0 = blockIdx.x * BLK_M;

    // staging geometry: lane i -> row (i>>3) of 8-row group, LDS slot (i&7);
    // source piece pre-swizzled so LDS slot s of row r holds source piece s^(r&7)
    const int sr8 = lane >> 3;           // 0..7
    const int sp  = (lane & 7) ^ sr8;    // swizzled source 16B-piece index

    float4v acc[2][4] = {};

#define STAGE(buf, kt)                                                          \
    {                                                                           \
        const int kk_ = (kt) * BK;                                              \
        const unsigned short* abase_; size_t apitch_; int kof_;                 \
        if (kk_ < KREL) { abase_ = A;  apitch_ = KREL; kof_ = kk_; }            \
        else            { abase_ = xb; apitch_ = D;    kof_ = kk_ - KREL; }     \
        _Pragma("unroll")                                                       \
        for (int t_ = 0; t_ < 2; ++t_) {                                        \
            int r_ = w * 16 + t_ * 8 + sr8;                                     \
            const unsigned short* g_ =                                          \
                abase_ + (size_t)(row0 + r_) * apitch_ + kof_ + sp * 8;         \
            gl_lds16(g_, &As[buf][(w * 16 + t_ * 8) * BK]);                     \
        }                                                                       \
        _Pragma("unroll")                                                       \
        for (int p_ = 0; p_ < 4; ++p_) {                                        \
            int r_ = w * 32 + p_ * 8 + sr8;                                     \
            const unsigned short* g_ = Bt + (size_t)r_ * KTOT + kk_ + sp * 8;   \
            gl_lds16(g_, &Bs[buf][(w * 32 + p_ * 8) * BK]);                     \
        }                                                                       \
    }

#define COMPUTE(buf)                                                            \
    {                                                                           \
        short8 a_[2][2], b_[2][4];                                              \
        _Pragma("unroll")                                                       \
        for (int ks_ = 0; ks_ < 2; ++ks_) {                                     \
            _Pragma("unroll")                                                   \
            for (int mi_ = 0; mi_ < 2; ++mi_) {                                 \
                int r_ = wm * 32 + mi_ * 16 + l16;                              \
                int c_ = (ks_ * 4 + q) ^ (l16 & 7);                             \
                a_[ks_][mi_] = *reinterpret_cast<const short8*>(                \
                    &As[buf][r_ * BK + c_ * 8]);                                \
            }                                                                   \
            _Pragma("unroll")                                                   \
            for (int ni_ = 0; ni_ < 4; ++ni_) {                                 \
                int r_ = wn * 64 + ni_ * 16 + l16;                              \
                int c_ = (ks_ * 4 + q) ^ (l16 & 7);                             \
                b_[ks_][ni_] = *reinterpret_cast<const short8*>(                \
                    &Bs[buf][r_ * BK + c_ * 8]);                                \
            }                                                                   \
        }                                                                       \
        _Pragma("unroll")                                                       \
        for (int ks_ = 0; ks_ < 2; ++ks_)                                       \
            _Pragma("unroll")                                                   \
            for (int mi_ = 0; mi_ < 2; ++mi_)                                   \
                _Pragma("unroll")                                               \
                for (int ni_ = 0; ni_ < 4; ++ni_)                               \
                    acc[mi_][ni_] = __builtin_amdgcn_mfma_f32_16x16x32_bf16(    \
                        a_[ks_][mi_], b_[ks_][ni_], acc[mi_][ni_], 0, 0, 0);    \
    }

    // prologue: fill buffer 0, drain, sync
    STAGE(0, 0);
    asm volatile("s_waitcnt vmcnt(0)" ::: "memory");
    __builtin_amdgcn_s_barrier();

    int buf = 0;
    const int NT = KTOT / BK;          // 18
    for (int kt = 0; kt < NT - 1; ++kt) {
        STAGE(buf ^ 1, kt + 1);        // issue next-tile loads (stay in flight)
        COMPUTE(buf);                  // ds_read + MFMA hide the load latency
        asm volatile("s_waitcnt vmcnt(0)" ::: "memory");
        __builtin_amdgcn_s_barrier();
        buf ^= 1;
    }
    COMPUTE(buf);                      // epilogue tile, no prefetch

#undef STAGE
#undef COMPUTE

#pragma unroll
    for (int ni = 0; ni < 4; ++ni) {
        int c = wn * 64 + ni * 16 + l16;
        float bv = bias[c];
#pragma unroll
        for (int mi = 0; mi < 2; ++mi) {
#pragma unroll
            for (int j = 0; j < 4; ++j) {
                int gr = row0 + wm * 32 + mi * 16 + q * 4 + j;
                if (gr < Nn)
                    out[(size_t)gr * D + c] = fmaxf(acc[mi][ni][j] + bv, 0.0f);
            }
        }
    }
}

extern "C" void kernel_launch(void* const* d_in, const int* in_sizes, int n_in,
                              void* d_out, int out_size, void* d_ws, size_t ws_size,
                              hipStream_t stream) {
    const float* x      = (const float*)d_in[0];
    const float* W_rel  = (const float*)d_in[1];
    const float* W_self = (const float*)d_in[2];
    const float* W_bias = (const float*)d_in[3];
    const int*   ei     = (const int*)d_in[4];
    const int*   et     = (const int*)d_in[5];

    const int Nn = in_sizes[0] / D;       // 50000
    const int E  = in_sizes[4] / 2;       // 800000
    const int npad = ((Nn + BLK_M - 1) / BLK_M) * BLK_M;  // pad rows for staging loads
    const int nbkt = (Nn + BRANGE - 1) >> BSHIFT;         // 782
    const int gz   = nbkt * CSTRIDE;

    // ---- workspace layout (256B aligned chunks) ----
    char* p = (char*)d_ws;
    auto take = [&](size_t bytes) { char* q = p; p += (bytes + 255) & ~(size_t)255; return q; };
    unsigned short* A    = (unsigned short*)take((size_t)npad * KREL * sizeof(unsigned short));
    unsigned short* xb   = (unsigned short*)take((size_t)npad * D * sizeof(unsigned short));
    unsigned short* Bt   = (unsigned short*)take((size_t)128 * KTOT * sizeof(unsigned short));
    int* offsets = (int*)take((size_t)Nn * sizeof(int));
    int* deg     = (int*)take((size_t)Nn * sizeof(int));
    int* gcur    = (int*)take((size_t)gz * sizeof(int));
    int* data    = (int*)take((size_t)nbkt * BCAP * sizeof(int));  // bucket records -> sorted

    const int xb_blocks = (Nn * 32 + 255) / 256;
    const int bt_blocks = (128 * KTOT + 255) / 256;
    const int gz_blocks = (gz + 255) / 256;
    prep_kernel<<<xb_blocks + bt_blocks + gz_blocks, 256, 0, stream>>>(
        x, W_rel, W_self, xb, Bt, gcur, Nn, xb_blocks, bt_blocks, gz);
    coarse_kernel<<<(E + 2047) / 2048, 256, 0, stream>>>(ei, et, gcur, data, E, nbkt);
    fine_kernel<<<nbkt, 256, 0, stream>>>(data, gcur, offsets, deg, Nn);
    aggregate_kernel<<<(Nn + 3) / 4, 256, 0, stream>>>(xb, offsets, deg, data, A, Nn);
    gemm_kernel<<<npad / BLK_M, 256, 0, stream>>>(A, xb, Bt, W_bias, (float*)d_out, Nn);
}